// Round 1
// baseline (96.304 us; speedup 1.0000x reference)
//
#include <hip/hip_runtime.h>

// Problem constants (from reference)
constexpr int B = 128, T = 12, V = 512, P = 40;
#define MAP_THRESH 0.5f
#define DIS_THRESH 1.0f
#define MASK_FILL  1000000.0f

// transform: x = l*30 - 15 ; y = l*60 - 30  (two-step rounding, no FMA, to match np)
__device__ __forceinline__ float txf(float l) { return __fadd_rn(__fmul_rn(l, 30.0f), -15.0f); }
__device__ __forceinline__ float tyf(float l) { return __fadd_rn(__fmul_rn(l, 60.0f), -30.0f); }

// Kernel 1: per (b, half): for each t, min over 256 lanes of (min over p of dist),
// with argmin lane index (first-index tie rule). grid = B*2, block = 256.
__global__ __launch_bounds__(256) void k1_mindist(
    const float* __restrict__ ego,     // B,T,2
    const float* __restrict__ lanes,   // B,V,P,2
    const float* __restrict__ scores,  // B,V,3
    float* __restrict__ ws_val,        // B*T*2
    int*   __restrict__ ws_idx)        // B*T*2
{
    const int blk = blockIdx.x;
    const int b = blk >> 1, h = blk & 1;
    const int tid = threadIdx.x;
    const int v = h * 256 + tid;

    __shared__ float s_px[T + 1], s_py[T + 1];
    if (tid == 0) {
        float cx = 0.f, cy = 0.f;
        s_px[0] = 0.f; s_py[0] = 0.f;
        for (int t = 0; t < T; ++t) {  // sequential fp32 cumsum, matches np
            cx = __fadd_rn(cx, ego[(b * T + t) * 2 + 0]);
            cy = __fadd_rn(cy, ego[(b * T + t) * 2 + 1]);
            s_px[t + 1] = cx; s_py[t + 1] = cy;
        }
    }
    __syncthreads();

    float px[T], py[T];
#pragma unroll
    for (int t = 0; t < T; ++t) { px[t] = s_px[t + 1]; py[t] = s_py[t + 1]; }

    float minsq[T];
    const bool masked = scores[(size_t)(b * V + v) * 3 + 2] < MAP_THRESH;  // not_bound
    if (masked) {
        // all P points are exactly (1e6, 1e6)
#pragma unroll
        for (int t = 0; t < T; ++t) {
            float dx = __fsub_rn(px[t], MASK_FILL);
            float dy = __fsub_rn(py[t], MASK_FILL);
            minsq[t] = __fadd_rn(__fmul_rn(dx, dx), __fmul_rn(dy, dy));
        }
    } else {
#pragma unroll
        for (int t = 0; t < T; ++t) minsq[t] = 3.4e38f;
        const float4* lp = (const float4*)(lanes + (size_t)(b * V + v) * P * 2);
#pragma unroll 2
        for (int q = 0; q < P / 2; ++q) {  // 20 float4 loads, 2 points each
            float4 f = lp[q];
            float x0 = txf(f.x), y0 = tyf(f.y);
            float x1 = txf(f.z), y1 = tyf(f.w);
#pragma unroll
            for (int t = 0; t < T; ++t) {
                float dx = __fsub_rn(px[t], x0);
                float dy = __fsub_rn(py[t], y0);
                float d2 = __fadd_rn(__fmul_rn(dx, dx), __fmul_rn(dy, dy));
                minsq[t] = fminf(minsq[t], d2);
                dx = __fsub_rn(px[t], x1);
                dy = __fsub_rn(py[t], y1);
                d2 = __fadd_rn(__fmul_rn(dx, dx), __fmul_rn(dy, dy));
                minsq[t] = fminf(minsq[t], d2);
            }
        }
    }

    // sqrt is monotone (weak-order preserving under RN), so sqrt(min) == min(sqrt).
    // Compare sqrt'd values for argmin to match the reference's argmin over norms.
    float sd[T];
#pragma unroll
    for (int t = 0; t < T; ++t) sd[t] = sqrtf(minsq[t]);

    __shared__ float rv[T][256];
    __shared__ int   ri[T][256];
#pragma unroll
    for (int t = 0; t < T; ++t) { rv[t][tid] = sd[t]; ri[t][tid] = v; }
    __syncthreads();
    for (int s = 128; s > 0; s >>= 1) {
        if (tid < s) {
#pragma unroll
            for (int t = 0; t < T; ++t) {
                float v1 = rv[t][tid + s]; int i1 = ri[t][tid + s];
                float v0 = rv[t][tid];     int i0 = ri[t][tid];
                if (v1 < v0 || (v1 == v0 && i1 < i0)) { rv[t][tid] = v1; ri[t][tid] = i1; }
            }
        }
        __syncthreads();
    }
    if (tid < T) {
        ws_val[(b * T + tid) * 2 + h] = rv[tid][0];
        ws_idx[(b * T + tid) * 2 + h] = ri[tid][0];
    }
}

// Kernel 2: per b: combine halves, run 12x39 segment-intersection tests on the
// argmin lane, prefix-OR "crossed", weighted loss sum -> ws_part[b].
__global__ __launch_bounds__(64) void k2_loss(
    const float* __restrict__ ego,
    const float* __restrict__ lanes,
    const float* __restrict__ scores,
    const float* __restrict__ weight,  // B,T
    const float* __restrict__ ws_val,
    const int*   __restrict__ ws_idx,
    float* __restrict__ ws_part)       // B
{
    const int b = blockIdx.x;
    const int tid = threadIdx.x;
    __shared__ float s_px[T + 1], s_py[T + 1];
    __shared__ float s_md[T];
    __shared__ int   s_vm[T];
    __shared__ int   s_cross[T];
    if (tid == 0) {
        float cx = 0.f, cy = 0.f; s_px[0] = 0.f; s_py[0] = 0.f;
        for (int t = 0; t < T; ++t) {
            cx = __fadd_rn(cx, ego[(b * T + t) * 2 + 0]);
            cy = __fadd_rn(cy, ego[(b * T + t) * 2 + 1]);
            s_px[t + 1] = cx; s_py[t + 1] = cy;
        }
    }
    if (tid < T) {
        float v0 = ws_val[(b * T + tid) * 2 + 0]; int i0 = ws_idx[(b * T + tid) * 2 + 0];
        float v1 = ws_val[(b * T + tid) * 2 + 1]; int i1 = ws_idx[(b * T + tid) * 2 + 1];
        if (v1 < v0) { v0 = v1; i0 = i1; }  // tie keeps half0 = smaller index
        s_md[tid] = v0; s_vm[tid] = i0;
        s_cross[tid] = 0;
    }
    __syncthreads();

    for (int w = tid; w < T * (P - 1); w += 64) {
        int t = w / (P - 1), p = w % (P - 1);
        int v = s_vm[t];
        // masked lane -> all points identical -> det == 0 -> never intersects
        if (scores[(size_t)(b * V + v) * 3 + 2] < MAP_THRESH) continue;
        const float* lp = lanes + (size_t)(b * V + v) * P * 2 + (size_t)p * 2;
        float bx0 = txf(lp[0]), by0 = tyf(lp[1]);
        float bx1 = txf(lp[2]), by1 = tyf(lp[3]);
        float sx = s_px[t],     sy = s_py[t];      // starts[t]
        float ex = s_px[t + 1], ey = s_py[t + 1];  // pred[t]
        float d1x = __fsub_rn(ex, sx),  d1y = __fsub_rn(ey, sy);
        float d2x = __fsub_rn(bx1, bx0), d2y = __fsub_rn(by1, by0);
        float det = __fsub_rn(__fmul_rn(d1x, d2y), __fmul_rn(d2x, d1y));
        if (det != 0.0f) {
            float dx = __fsub_rn(bx0, sx), dy = __fsub_rn(by0, sy);
            float t1 = __fdiv_rn(__fsub_rn(__fmul_rn(dx, d2y), __fmul_rn(dy, d2x)), det);
            float t2 = __fdiv_rn(__fsub_rn(__fmul_rn(dx, d1y), __fmul_rn(dy, d1x)), det);
            if (t1 >= 0.f && t1 <= 1.f && t2 >= 0.f && t2 <= 1.f)
                atomicOr(&s_cross[t], 1);
        }
    }
    __syncthreads();

    if (tid == 0) {
        float sum = 0.f;
        int crossed = 0;
        for (int t = 0; t < T; ++t) {
            crossed |= s_cross[t];  // cumsum(intersect) >= 1
            float md = s_md[t];
            float l = (md <= DIS_THRESH) ? __fsub_rn(DIS_THRESH, md) : 0.f;
            if (crossed) l = 0.f;
            sum = __fadd_rn(sum, __fmul_rn(l, weight[b * T + t]));
        }
        ws_part[b] = sum;
    }
}

// Kernel 3: deterministic tree-sum of 128 partials, mean, write scalar.
__global__ __launch_bounds__(128) void k3_reduce(
    const float* __restrict__ ws_part, float* __restrict__ out)
{
    __shared__ float sm[128];
    const int tid = threadIdx.x;
    sm[tid] = ws_part[tid];
    __syncthreads();
    for (int s = 64; s > 0; s >>= 1) {
        if (tid < s) sm[tid] = __fadd_rn(sm[tid], sm[tid + s]);
        __syncthreads();
    }
    if (tid == 0) out[0] = __fdiv_rn(sm[0], (float)(B * T));
}

extern "C" void kernel_launch(void* const* d_in, const int* in_sizes, int n_in,
                              void* d_out, int out_size, void* d_ws, size_t ws_size,
                              hipStream_t stream) {
    const float* ego    = (const float*)d_in[0];  // B,T,2
    const float* lanes  = (const float*)d_in[1];  // B,V,P,2
    const float* scores = (const float*)d_in[2];  // B,V,3
    const float* weight = (const float*)d_in[3];  // B,T
    float* out = (float*)d_out;

    float* ws_val  = (float*)d_ws;                // 3072 floats
    int*   ws_idx  = (int*)d_ws + 3072;           // 3072 ints
    float* ws_part = (float*)d_ws + 6144;         // 128 floats

    k1_mindist<<<B * 2, 256, 0, stream>>>(ego, lanes, scores, ws_val, ws_idx);
    k2_loss<<<B, 64, 0, stream>>>(ego, lanes, scores, weight, ws_val, ws_idx, ws_part);
    k3_reduce<<<1, 128, 0, stream>>>(ws_part, out);
}